// Round 9
// baseline (87.783 us; speedup 1.0000x reference)
//
#include <hip/hip_runtime.h>

// Problem constants
#define L_SEQ 2048
#define NH 2
#define FD 16
#define BH 8            // B * H
#define QT 32           // queries per fused-attn block
#define NT 64           // q tiles (L_SEQ / QT)
#define SCW 128         // s per staged chunk

typedef _Float16 half4f __attribute__((ext_vector_type(4)));
typedef float floatx4 __attribute__((ext_vector_type(4)));

struct FalseT { static constexpr bool value = false; };
struct TrueT  { static constexpr bool value = true;  };

// ---------------- Kernel A: fused QKV projection (f16 out, q pre-scaled) ----------------
__global__ __launch_bounds__(256) void qkv_proj_kernel(
    const float* __restrict__ hs, const float* __restrict__ Wq,
    const float* __restrict__ Wk, const float* __restrict__ Wv,
    _Float16* __restrict__ q, _Float16* __restrict__ k,
    _Float16* __restrict__ v) {
  __shared__ float sW[3][32][32];
  __shared__ float sH[32][32];
  int tid = threadIdx.x;
  float* swf = &sW[0][0][0];
  for (int i = tid; i < 3072; i += 256)
    swf[i] = (i < 1024) ? Wq[i] : (i < 2048) ? Wk[i - 1024] : Wv[i - 2048];
  int row0 = blockIdx.x * 32;
  int r0 = tid >> 5, c = tid & 31;
  for (int p = 0; p < 4; p++) {
    int r = r0 + p * 8;
    sH[r][c] = hs[(size_t)(row0 + r) * 32 + c];
  }
  __syncthreads();
  int hh = c >> 4, f = c & 15;
  for (int p = 0; p < 4; p++) {
    int r = r0 + p * 8;
    float aq = 0.f, ak = 0.f, av = 0.f;
#pragma unroll
    for (int i = 0; i < 32; i++) {
      float h = sH[r][i];
      aq += h * sW[0][i][c];
      ak += h * sW[1][i][c];
      av += h * sW[2][i][c];
    }
    int row = row0 + r;
    int b = row >> 11, l = row & (L_SEQ - 1);
    size_t idx = (((size_t)(b * NH + hh)) * L_SEQ + l) * FD + f;
    q[idx] = (_Float16)(aq * 0.25f);  // fold 1/sqrt(d)
    k[idx] = (_Float16)ak;
    v[idx] = (_Float16)av;
  }
}

// ---------------- Kernel B: fused flash attention + output projection ----------------
// Block (xt, b): 32 queries [t*32, +32) of batch b, BOTH heads.
// Wave w: head = w>>1, chunk-parity = w&1; each wave computes BOTH 16-query
// subtiles of its head (2 independent mfma chains), over chunks c ≡ par (mod 2).
// Each round stages 2 chunks (parity 0/1 buffers) -> half the barriers; worst
// tile = 8 serial chunk-steps per wave. Parity partials (o, den) combine via LDS.
// Swapped QK: S^T = mfma(K, Q^T) -> lane (lm,lg) reg r holds (q=lm, s=16st+4lg+r)
// == A-frag for PV mfma; PV output: (q=4lg+r, f=lm).
__global__ __launch_bounds__(256) void attn_fused_kernel(
    const _Float16* __restrict__ q, const _Float16* __restrict__ k,
    const _Float16* __restrict__ v, const float* __restrict__ Wo,
    float* __restrict__ out) {
  __shared__ _Float16 sK[2][NH][128][24];
  __shared__ _Float16 sVT[2][NH][16][136];
  __shared__ float sO[2][NH][2][16][17];
  __shared__ float sDen[2][NH][2][16];
  __shared__ float sY[QT][33];
  __shared__ float sWo[32][32];

  int tid = threadIdx.x;
  int b = blockIdx.y;
  int t = NT - 1 - (int)blockIdx.x;  // longest tiles first
  int lane = tid & 63;
  int wid = tid >> 6;
  int lm = lane & 15, lg = lane >> 4;
  int h = wid >> 1, par = wid & 1;
  int bh = b * NH + h;

  for (int i = tid; i < 1024; i += 256) (&sWo[0][0])[i] = Wo[i];

  half4f qf[2];
#pragma unroll
  for (int sub = 0; sub < 2; sub++)
    qf[sub] = *(const half4f*)(
        q + ((size_t)bh * L_SEQ + t * QT + sub * 16 + lm) * FD + 4 * lg);

  floatx4 o[2];
  float dn[2];
#pragma unroll
  for (int i = 0; i < 2; i++) {
    o[i] = (floatx4){0.f, 0.f, 0.f, 0.f};
    dn[i] = 0.f;
  }
  int tq[2];
#pragma unroll
  for (int sub = 0; sub < 2; sub++) tq[sub] = t * QT + sub * 16 + lm;

  int lastc = t >> 2;          // diagonal (masked) chunk
  int ss = tid >> 1, hf = tid & 1;

  auto body = [&](int sc, auto mc) {
    constexpr bool MASK = decltype(mc)::value;
    int sb = sc * SCW + 4 * lg;
#pragma unroll
    for (int st = 0; st < 8; st++) {
      half4f kf = *(const half4f*)&sK[par][h][st * 16 + lm][4 * lg];
      half4f vf = *(const half4f*)&sVT[par][h][lm][st * 16 + 4 * lg];
#pragma unroll
      for (int sub = 0; sub < 2; sub++) {
        floatx4 sT = __builtin_amdgcn_mfma_f32_16x16x16f16(
            kf, qf[sub], (floatx4){0.f, 0.f, 0.f, 0.f}, 0, 0, 0);
        float wvv[4];
#pragma unroll
        for (int r = 0; r < 4; r++) {
          float a = sT[r];
          float wr = (0.5f * a + 1.f) * a + 1.f;  // 1 + g + g^2/2
          if (MASK) wr = (sb + st * 16 + r <= tq[sub]) ? wr : 0.f;
          wvv[r] = wr;
          dn[sub] += wr;
        }
        half4f wf = {(_Float16)wvv[0], (_Float16)wvv[1],
                     (_Float16)wvv[2], (_Float16)wvv[3]};
        o[sub] = __builtin_amdgcn_mfma_f32_16x16x16f16(wf, vf, o[sub], 0, 0, 0);
      }
    }
  };

  int nr = (lastc >> 1) + 1;  // parity rounds
  for (int rd = 0; rd < nr; rd++) {
    int c0 = rd * 2;
    __syncthreads();  // previous round's buffers fully consumed
#pragma unroll
    for (int p = 0; p < 2; p++) {
      int c = c0 + p;
      if (c <= lastc) {  // uniform across block
#pragma unroll
        for (int hh = 0; hh < NH; hh++) {
          const _Float16* kp =
              k + (((size_t)(b * NH + hh)) * L_SEQ + c * SCW + ss) * FD + 8 * hf;
          const _Float16* vp =
              v + (((size_t)(b * NH + hh)) * L_SEQ + c * SCW + ss) * FD + 8 * hf;
          *(uint4*)&sK[p][hh][ss][8 * hf] = *(const uint4*)kp;
          union { uint4 u; _Float16 e[8]; } vu;
          vu.u = *(const uint4*)vp;
#pragma unroll
          for (int i = 0; i < 8; i++) sVT[p][hh][8 * hf + i][ss] = vu.e[i];
        }
      }
    }
    __syncthreads();
    int c = c0 + par;  // per-wave divergent, barriers stay outside
    if (c <= lastc) {
      if (c < lastc) body(c, FalseT{}); else body(c, TrueT{});
    }
  }

  // reduce den over lg strips (within wave), publish parity partials
#pragma unroll
  for (int sub = 0; sub < 2; sub++) {
    dn[sub] += __shfl_xor(dn[sub], 16, 64);
    dn[sub] += __shfl_xor(dn[sub], 32, 64);
  }
  if (lg == 0) {
    sDen[par][h][0][lm] = dn[0];
    sDen[par][h][1][lm] = dn[1];
  }
#pragma unroll
  for (int sub = 0; sub < 2; sub++)
#pragma unroll
    for (int r = 0; r < 4; r++)
      sO[par][h][sub][4 * lg + r][lm] = o[sub][r];
  __syncthreads();

  // combine parities, divide, build sY[q32][col]
  {
    int q32 = tid >> 3, cb = (tid & 7) * 4;
    int subq = q32 >> 4, qrow = q32 & 15;
    int hc = cb >> 4, fb = cb & 15;
    float dtot = sDen[0][hc][subq][qrow] + sDen[1][hc][subq][qrow];
    float inv = 1.f / dtot;
#pragma unroll
    for (int j = 0; j < 4; j++)
      sY[q32][cb + j] =
          (sO[0][hc][subq][qrow][fb + j] + sO[1][hc][subq][qrow][fb + j]) * inv;
  }
  __syncthreads();

  // out-proj: 32 rows x 32 cols
  int c = tid & 31, r0 = tid >> 5;
  float wo[32];
#pragma unroll
  for (int i = 0; i < 32; i++) wo[i] = sWo[i][c];
#pragma unroll
  for (int p = 0; p < 4; p++) {
    int r = r0 + p * 8;
    float a = 0.f;
#pragma unroll
    for (int i = 0; i < 32; i++) a += sY[r][i] * wo[i];
    out[((size_t)b * L_SEQ + t * QT + r) * 32 + c] = a;
  }
}

extern "C" void kernel_launch(void* const* d_in, const int* in_sizes, int n_in,
                              void* d_out, int out_size, void* d_ws, size_t ws_size,
                              hipStream_t stream) {
  const float* hs = (const float*)d_in[0];
  const float* Wq = (const float*)d_in[1];
  const float* Wk = (const float*)d_in[2];
  const float* Wv = (const float*)d_in[3];
  const float* Wo = (const float*)d_in[4];
  float* out = (float*)d_out;

  char* wb = (char*)d_ws;
  const size_t PER = (size_t)BH * L_SEQ * FD;  // 262144 elements
  _Float16* qh = (_Float16*)wb;
  _Float16* kh = qh + PER;
  _Float16* vh = kh + PER;

  qkv_proj_kernel<<<256, 256, 0, stream>>>(hs, Wq, Wk, Wv, qh, kh, vh);
  attn_fused_kernel<<<dim3(NT, 4), 256, 0, stream>>>(qh, kh, vh, Wo, out);
}